// Round 1
// baseline (1201.781 us; speedup 1.0000x reference)
//
#include <hip/hip_runtime.h>

#define EDGES 400000
#define NN 25000
#define BB 2
#define FCIN 64
#define FCHID 256
#define NCH 288
#define EPB 16

static_assert(EDGES % EPB == 0, "EPB must divide E");

__global__ __launch_bounds__(256, 2) void conv_fused(
    const int* __restrict__ esrc, const int* __restrict__ edst,
    const float* __restrict__ nemb, const float* __restrict__ etype,
    const float* __restrict__ W1, const float* __restrict__ W2,
    float* __restrict__ out)
{
    __shared__ __align__(16) float s_et[EPB][FCIN];    // 4 KB
    __shared__ __align__(16) float s_h[EPB][FCHID];    // 16 KB
    __shared__ __align__(16) float s_w[EPB][96];       // 6 KB
    __shared__ float s_geom[EPB][BB][9];
    __shared__ int s_dst[EPB];

    const int t = threadIdx.x;
    const size_t e0 = (size_t)blockIdx.x * EPB;

    // ---- stage edge_type tile: EPB*64 = 1024 floats, one float4/thread ----
    {
        const float4* src4 = (const float4*)(etype + e0 * FCIN);
        ((float4*)&s_et[0][0])[t] = src4[t];
    }

    // ---- geometry for (edge e, batch b): threads 0..31 ----
    if (t < EPB * BB) {
        int e = t >> 1, b = t & 1;
        int s = esrc[e0 + e];
        int d = edst[e0 + e];
        const float* xp = nemb + ((size_t)b * NN + s) * 3;
        const float* yp = nemb + ((size_t)b * NN + d) * 3;
        float x0 = xp[0], x1 = xp[1], x2 = xp[2];
        float y0 = yp[0], y1 = yp[1], y2 = yp[2];
        const float inv3 = 0.5773502691896258f;   // 1/sqrt(3)
        const float inv2 = 0.7071067811865476f;   // 1/sqrt(2)
        const float inv6 = 0.4082482904638630f;   // 1/sqrt(6)
        s_geom[e][b][0] = (x0*y0 + x1*y1 + x2*y2) * inv3;      // s
        s_geom[e][b][1] = (x1*y2 - x2*y1) * inv2;              // cross x
        s_geom[e][b][2] = (x2*y0 - x0*y2) * inv2;              // cross y
        s_geom[e][b][3] = (x0*y1 - x1*y0) * inv2;              // cross z
        s_geom[e][b][4] = (x0*y1 + x1*y0) * inv2;              // t0
        s_geom[e][b][5] = (x1*y2 + x2*y1) * inv2;              // t1
        s_geom[e][b][6] = (x0*y2 + x2*y0) * inv2;              // t2
        s_geom[e][b][7] = (x0*y0 - x1*y1) * inv2;              // t3
        s_geom[e][b][8] = (2.0f*x2*y2 - x0*y0 - x1*y1) * inv6; // t4
        if (b == 0) s_dst[e] = d;
    }
    __syncthreads();

    // ---- layer 1: thread t owns hidden unit j = t; W1 column in registers ----
    {
        float w1reg[FCIN];
        #pragma unroll
        for (int k = 0; k < FCIN; ++k) w1reg[k] = W1[k * FCHID + t];
        for (int e = 0; e < EPB; ++e) {
            float a = 0.f;
            #pragma unroll
            for (int k4 = 0; k4 < FCIN / 4; ++k4) {
                float4 ev = *(const float4*)&s_et[e][k4 * 4];   // wave-uniform broadcast
                a = fmaf(ev.x, w1reg[k4*4+0], a);
                a = fmaf(ev.y, w1reg[k4*4+1], a);
                a = fmaf(ev.z, w1reg[k4*4+2], a);
                a = fmaf(ev.w, w1reg[k4*4+3], a);
            }
            float pre = a * 0.125f;                 // 1/sqrt(64)
            s_h[e][t] = pre / (1.f + __expf(-pre)); // silu
        }
    }
    __syncthreads();

    // ---- layer 2: threads 0..191: j = t>>1 owns column, kh = t&1 splits K ----
    if (t < 192) {
        int j = t >> 1, kh = t & 1;
        float w2reg[FCHID / 2];
        #pragma unroll
        for (int k = 0; k < FCHID / 2; ++k) w2reg[k] = W2[(kh * 128 + k) * 96 + j];
        for (int e = 0; e < EPB; ++e) {
            float a = 0.f;
            #pragma unroll
            for (int k4 = 0; k4 < 32; ++k4) {
                float4 hv = *(const float4*)&s_h[e][kh * 128 + k4 * 4]; // 2 distinct addrs/wave
                a = fmaf(hv.x, w2reg[k4*4+0], a);
                a = fmaf(hv.y, w2reg[k4*4+1], a);
                a = fmaf(hv.z, w2reg[k4*4+2], a);
                a = fmaf(hv.w, w2reg[k4*4+3], a);
            }
            a += __shfl_xor(a, 1);                  // combine the two K-halves
            if (kh == 0) s_w[e][j] = a * (0.0625f * 0.25f); // 1/sqrt(256) * 1/sqrt(16)
        }
    }
    __syncthreads();

    // ---- tensor product + scatter: group g = t>>4 owns edge g, lane l = t&15 ----
    {
        int g = t >> 4, l = t & 15;
        int d = s_dst[g];
        float* outb0 = out + (size_t)d * NCH;              // batch 0
        float* outb1 = out + ((size_t)NN + d) * NCH;       // batch 1
        #pragma unroll
        for (int ci = 0; ci < NCH / 16; ++ci) {
            int c = l + ci * 16;
            unsigned wi, gi;
            if (c < 32)       { wi = c;                         gi = 0; }
            else if (c < 128) { unsigned q = c - 32;  wi = 32 + q / 3u; gi = 1 + q % 3u; }
            else              { unsigned q = c - 128; wi = 64 + q / 5u; gi = 4 + q % 5u; }
            float wv = s_w[g][wi];
            atomicAdd(&outb0[c], wv * s_geom[g][0][gi]);
            atomicAdd(&outb1[c], wv * s_geom[g][1][gi]);
        }
    }
}

extern "C" void kernel_launch(void* const* d_in, const int* in_sizes, int n_in,
                              void* d_out, int out_size, void* d_ws, size_t ws_size,
                              hipStream_t stream) {
    const int*   esrc  = (const int*)d_in[0];
    const int*   edst  = (const int*)d_in[1];
    const float* nemb  = (const float*)d_in[2];
    const float* etype = (const float*)d_in[3];
    const float* W1    = (const float*)d_in[4];
    const float* W2    = (const float*)d_in[5];
    float* out = (float*)d_out;

    // harness poisons d_out once and never re-zeros between replays
    hipMemsetAsync(out, 0, (size_t)out_size * sizeof(float), stream);
    conv_fused<<<EDGES / EPB, 256, 0, stream>>>(esrc, edst, nemb, etype, W1, W2, out);
}